// Round 1
// 651.893 us; speedup vs baseline: 1.0152x; 1.0152x over previous
//
#include <hip/hip_runtime.h>

#define NH 10
#define NB 8        // batches
#define NC 8        // channels
#define NT 16384    // targets
#define NS 4096     // sources
#define EPSW 1e-10f
#define CAP 256     // max candidates kept per target before exact fallback
#define T2  0.02f   // d^2 threshold: P(chi2_2 < 0.02) ~= 0.00995 -> E[cand] ~= 40.7

typedef float float4n __attribute__((ext_vector_type(4)));

// Branch-free ascending sorted insert of a u64 key (d2bits<<32 | idx).
// Key ordering == (d2 asc, idx asc): exact jax top_k tie-breaking for free.
__device__ __forceinline__ void insert_key(unsigned long long key, unsigned long long kv[NH]) {
    bool c[NH];
#pragma unroll
    for (int k = 0; k < NH; ++k) c[k] = key < kv[k];
    unsigned long long nv[NH];
    nv[0] = c[0] ? key : kv[0];
#pragma unroll
    for (int k = 1; k < NH; ++k)
        nv[k] = c[k] ? (c[k - 1] ? kv[k - 1] : key) : kv[k];
#pragma unroll
    for (int k = 0; k < NH; ++k) kv[k] = nv[k];
}

// One wave (64 lanes) per target, 4 waves per 256-thread block.
__global__ __launch_bounds__(256) void knn_interp_kernel(
    const float* __restrict__ x,    // [NB, NS, NC]
    const float* __restrict__ rel,  // [NT, NS, 2]
    float* __restrict__ out)        // [NB, NT, NC]
{
    const int lane = threadIdx.x & 63;
    const int wave = threadIdx.x >> 6;
    const int t = blockIdx.x * 4 + wave;

    __shared__ unsigned long long cbuf[4][CAP];   // per-wave candidate keys
    unsigned long long* cb = cbuf[wave];
    const unsigned long long lmask = (1ull << lane) - 1ull;

    const float4n* relrow = (const float4n*)(rel + (size_t)t * (NS * 2));

    int cnt = 0;  // wave-uniform candidate count (counts ALL d2<T2, even past CAP)

    auto scan2 = [&](float d2, int ix) {
        unsigned long long m = __ballot(d2 < T2);
        if (m) {                                   // wave-uniform branch, ~47%/group
            if (d2 < T2) {
                int pos = cnt + (int)__popcll(m & lmask);
                if (pos < CAP)
                    cb[pos] = ((unsigned long long)__float_as_uint(d2) << 32) | (unsigned)ix;
            }
            cnt += (int)__popcll(m);
        }
    };

    // 2048 float4s per target / 64 lanes = 32 per lane; chunks of 4, 8 chunks.
    float4n cur[4];
#pragma unroll
    for (int u = 0; u < 4; ++u)
        cur[u] = __builtin_nontemporal_load(&relrow[u * 64 + lane]);

#pragma unroll 1
    for (int j = 0; j < 7; ++j) {
        float4n nxt[4];
#pragma unroll
        for (int u = 0; u < 4; ++u)
            nxt[u] = __builtin_nontemporal_load(&relrow[(j + 1) * 256 + u * 64 + lane]);
#pragma unroll
        for (int u = 0; u < 4; ++u) {
            const int f4i = j * 256 + u * 64 + lane;
            float d2a = cur[u].x * cur[u].x + cur[u].y * cur[u].y;
            float d2b = cur[u].z * cur[u].z + cur[u].w * cur[u].w;
            scan2(d2a, f4i * 2);
            scan2(d2b, f4i * 2 + 1);
        }
#pragma unroll
        for (int u = 0; u < 4; ++u) cur[u] = nxt[u];
    }
    // epilogue chunk j=7
#pragma unroll
    for (int u = 0; u < 4; ++u) {
        const int f4i = 7 * 256 + u * 64 + lane;
        float d2a = cur[u].x * cur[u].x + cur[u].y * cur[u].y;
        float d2b = cur[u].z * cur[u].z + cur[u].w * cur[u].w;
        scan2(d2a, f4i * 2);
        scan2(d2b, f4i * 2 + 1);
    }

    __syncthreads();  // drains lgkmcnt; guarantees cb[] visible before selection

    unsigned long long kv[NH];
#pragma unroll
    for (int k = 0; k < NH; ++k) kv[k] = ~0ull;

    if (cnt >= NH && cnt <= CAP) {
        // >= NH elements strictly below T2  =>  global top-NH all in cb[0..cnt)
        for (int i = lane; i < cnt; i += 64)
            insert_key(cb[i], kv);
    } else {
        // exact fallback: full rescan with the insert network (P ~ 4e-9/target here)
        for (int f = lane; f < NS / 2; f += 64) {
            float4n q = relrow[f];
            float d2a = q.x * q.x + q.y * q.y;
            float d2b = q.z * q.z + q.w * q.w;
            insert_key(((unsigned long long)__float_as_uint(d2a) << 32) | (unsigned)(2 * f),     kv);
            insert_key(((unsigned long long)__float_as_uint(d2b) << 32) | (unsigned)(2 * f + 1), kv);
        }
    }

    // ---- wave all-reduce: global top-NH via u64 key min-extract, NH rounds ----
    float rd[NH];
    int   ridx[NH];
#pragma unroll
    for (int r = 0; r < NH; ++r) {
        unsigned long long m = kv[0];
#pragma unroll
        for (int o = 32; o > 0; o >>= 1) {
            unsigned long long other = __shfl_xor(m, o, 64);
            m = (other < m) ? other : m;
        }
        rd[r]   = __uint_as_float((unsigned)(m >> 32));
        ridx[r] = (int)(unsigned)(m & 0xFFFFFFFFull);
        bool won = (kv[0] == m);  // unique idx in key -> exactly one winner
#pragma unroll
        for (int k = 0; k < NH - 1; ++k) kv[k] = won ? kv[k + 1] : kv[k];
        kv[NH - 1] = won ? ~0ull : kv[NH - 1];
    }

    // ---- weights ----
    float w[NH];
    float wsum = 0.f;
#pragma unroll
    for (int r = 0; r < NH; ++r) {
        float d = sqrtf(rd[r]);
        w[r] = 1.0f / (d + EPSW);
        wsum += w[r];
    }
    const float inv = 1.0f / wsum;

    // ---- gather + weighted sum: lane = b*8 + c covers all (b,c) pairs ----
    const int b = lane >> 3;
    const int c = lane & 7;
    const float* xb = x + ((size_t)b * NS) * NC + c;
    float acc = 0.f;
#pragma unroll
    for (int r = 0; r < NH; ++r) {
        acc += w[r] * xb[(size_t)ridx[r] * NC];
    }
    out[((size_t)b * NT + t) * NC + c] = acc * inv;
}

extern "C" void kernel_launch(void* const* d_in, const int* in_sizes, int n_in,
                              void* d_out, int out_size, void* d_ws, size_t ws_size,
                              hipStream_t stream) {
    const float* x   = (const float*)d_in[0];
    const float* rel = (const float*)d_in[1];
    float* out = (float*)d_out;

    dim3 grid(NT / 4);   // 4 targets (waves) per 256-thread block
    dim3 block(256);
    knn_interp_kernel<<<grid, block, 0, stream>>>(x, rel, out);
}